// Round 6
// baseline (51.264 us; speedup 1.0000x reference)
//
#include <hip/hip_runtime.h>
#include <hip/hip_bf16.h>

constexpr int Bb  = 8;
constexpr int Nn  = 2048;
constexpr int FIN = 128;
constexpr int FOUT = 64;
constexpr float LOG2E = 1.4426950408889634f;

typedef __bf16 bf16x8 __attribute__((ext_vector_type(8)));
typedef __bf16 bf16x2 __attribute__((ext_vector_type(2)));
typedef float  f32x4  __attribute__((ext_vector_type(4)));
typedef int    i32x4  __attribute__((ext_vector_type(4)));
typedef unsigned int u32;

__device__ __forceinline__ u32 f2bf_bits(float f) {
    u32 u = __builtin_bit_cast(u32, f);
    return (u + 0x7FFFu + ((u >> 16) & 1u)) >> 16;  // RNE
}

// Kernel 1: Wh = h@W (fp32 accum) -> bf16 in MFMA B-fragment order.
// B-frag: frag[b][t32][o16][lane][r] = Wh[t32*32 + (lane>>4)*8 + r][o16*16 + (lane&15)]
// fs = (Wh @ a[:64]) * log2e, fd = (Wh @ a[64:]) * log2e  (pre-scaled for exp2).
__global__ __launch_bounds__(256) void gat_k1(
        const float* __restrict__ h, const float* __restrict__ W,
        const float* __restrict__ a, __bf16* __restrict__ whfrag,
        float* __restrict__ fs, float* __restrict__ fd) {
    const int blk = blockIdx.x;
    const int b   = blk >> 6;
    const int t32 = blk & 63;
    const int n0  = t32 * 32;
    const int l   = threadIdx.x & 63;
    const int w   = __builtin_amdgcn_readfirstlane((int)(threadIdx.x >> 6));

    const float a0 = a[l];
    const float a1 = a[FOUT + l];

    float acc[8];
#pragma unroll
    for (int r = 0; r < 8; ++r) acc[r] = 0.f;

    const float* hbase = h + (size_t)(b * Nn + n0 + w * 8) * FIN;

#pragma unroll 1
    for (int c0 = 0; c0 < FIN; c0 += 32) {
        float wreg[32];
#pragma unroll
        for (int cc = 0; cc < 32; ++cc) wreg[cc] = W[(c0 + cc) * FOUT + l];
#pragma unroll
        for (int r = 0; r < 8; ++r) {
            const float* hrow = hbase + r * FIN + c0;   // wave-uniform -> s_load
#pragma unroll
            for (int cc = 0; cc < 32; ++cc) acc[r] = fmaf(hrow[cc], wreg[cc], acc[r]);
        }
    }

#pragma unroll
    for (int r = 0; r < 8; ++r) {
        float s0 = acc[r] * a0;
        float s1 = acc[r] * a1;
#pragma unroll
        for (int off = 32; off >= 1; off >>= 1) {
            s0 += __shfl_xor(s0, off, 64);
            s1 += __shfl_xor(s1, off, 64);
        }
        if (l == 0) {
            fs[b * Nn + n0 + w * 8 + r] = s0 * LOG2E;
            fd[b * Nn + n0 + w * 8 + r] = s1 * LOG2E;
        }
    }

    u32 pk[4];
#pragma unroll
    for (int i = 0; i < 4; ++i)
        pk[i] = f2bf_bits(acc[2 * i]) | (f2bf_bits(acc[2 * i + 1]) << 16);
    const int slotg = ((b * 64 + t32) * 4 + (l >> 4)) * 64 + ((w << 4) | (l & 15));
    reinterpret_cast<uint4*>(whfrag)[slotg] = make_uint4(pk[0], pk[1], pk[2], pk[3]);
}

// Kernel 2: identical sync structure to r5 (double-buffered per-wave A tile,
// lgkmcnt fence), but waves now take ADJACENT 64-j windows: per iteration a
// block reads 16 rows x 1KB contiguous adj (DRAM-page-friendly bursts),
// instead of 4 chunks of 256B spread 2KB apart per row.
__global__ __launch_bounds__(256, 4) void gat_k2(
        const int* __restrict__ adj, const __bf16* __restrict__ whfrag,
        const float* __restrict__ fs, const float* __restrict__ fd,
        float* __restrict__ out) {
    const int blk = blockIdx.x;              // 1024 blocks
    const int b   = blk >> 7;
    const int i0  = (blk & 127) * 16;
    const int l   = threadIdx.x & 63;
    const int w   = __builtin_amdgcn_readfirstlane((int)(threadIdx.x >> 6)); // j sub-window

    __shared__ __align__(16) char  aLDS[4 * 4096];  // per-wave 2x2KB double buffer
    __shared__ f32x4 comb[4][4][64];                // 16 KB combine buffer
    __shared__ float zpart[4][16];

    const int g  = l >> 4;      // row group: rows g*4 .. g*4+3
    const int jc = l & 15;      // j sub: j = jc*4 .. jc*4+3 within 64-j window

    char* myA = aLDS + w * 4096;

    float fs_loc[4];
#pragma unroll
    for (int rr = 0; rr < 4; ++rr) fs_loc[rr] = fs[b * Nn + i0 + g * 4 + rr];

    // wave w's 64-j window at iteration it: j in [it*256 + w*64, +64)
    const float* fdp  = fd + b * Nn + w * 64 + jc * 4;
    const int*   adj0 = adj + (size_t)(b * Nn + i0 + g * 4) * Nn + w * 64 + jc * 4;

    const bf16x8* bfr = reinterpret_cast<const bf16x8*>(whfrag)
                        + (size_t)(b * 256) * 64 + l;

    f32x4 acc[4] = {{0,0,0,0},{0,0,0,0},{0,0,0,0},{0,0,0,0}};
    f32x4 accz   = {0.f, 0.f, 0.f, 0.f};

    bf16x8 onesv;
#pragma unroll
    for (int i = 0; i < 8; ++i) onesv[i] = (__bf16)1.0f;

    i32x4 adjQ[2][4];
    f32x4 fdQ[2];

#pragma unroll
    for (int rr = 0; rr < 4; ++rr)
        adjQ[0][rr] = *reinterpret_cast<const i32x4*>(adj0 + (size_t)rr * Nn);
    fdQ[0] = *reinterpret_cast<const f32x4*>(fdp);

#pragma unroll 2
    for (int it = 0; it < 8; ++it) {
        const int cur = it & 1, nxt = cur ^ 1;   // compile-time under unroll 2
        if (it < 7) {  // 1-ahead HBM prefetch (next window 1KB further)
#pragma unroll
            for (int rr = 0; rr < 4; ++rr)
                adjQ[nxt][rr] = *reinterpret_cast<const i32x4*>(
                                    adj0 + (size_t)rr * Nn + (it + 1) * 256);
            fdQ[nxt] = *reinterpret_cast<const f32x4*>(fdp + (it + 1) * 256);
        }

        // phase A: p = mask ? exp2(max(e',0.2e')) : 0 (fs/fd pre-scaled by log2e)
        char* buf = myA + cur * 2048;
#pragma unroll
        for (int rr = 0; rr < 4; ++rr) {
            const int row = g * 4 + rr;
            u32 wds[2];
#pragma unroll
            for (int hp = 0; hp < 2; ++hp) {
                float pv[2];
#pragma unroll
                for (int q = 0; q < 2; ++q) {
                    const int jj = hp * 2 + q;
                    float e  = fs_loc[rr] + fdQ[cur][jj];
                    float lr = fmaxf(e, 0.2f * e);       // leaky relu (scale-safe)
                    float p  = exp2f(lr);
                    pv[q] = (adjQ[cur][rr][jj] > 0) ? p : 0.f;
                }
                wds[hp] = __builtin_bit_cast(u32,
                            (bf16x2){(__bf16)pv[0], (__bf16)pv[1]});
            }
            const int boff = (row * 128 + jc * 8) ^ ((row & 7) << 4);   // XOR swizzle
            *reinterpret_cast<uint2*>(buf + boff) = make_uint2(wds[0], wds[1]);
        }

        // fence: this wave's ds_writes committed before phase-B ds_reads.
        asm volatile("s_waitcnt lgkmcnt(0)" ::: "memory");
        __builtin_amdgcn_sched_barrier(0x20);   // VMEM reads may still hoist

        // phase B: 2 ds_read_b128 + 10 MFMA (8 PV + 2 Z row-sum)
        // kb-tile global index: J = it*256 + w*64 + kb*32 -> t32 = it*8 + w*2 + kb
        {
            const int rb0 = (((l & 15) * 128 + 0 * 64 + g * 16) ^ ((l & 7) << 4));
            bf16x8 av = *reinterpret_cast<const bf16x8*>(buf + rb0);
#pragma unroll
            for (int o16 = 0; o16 < 4; ++o16)
                acc[o16] = __builtin_amdgcn_mfma_f32_16x16x32_bf16(
                               av, bfr[(((it * 8 + w * 2 + 0) * 4) + o16) * 64], acc[o16], 0, 0, 0);
            accz = __builtin_amdgcn_mfma_f32_16x16x32_bf16(av, onesv, accz, 0, 0, 0);
        }
        {
            const int rb1 = (((l & 15) * 128 + 1 * 64 + g * 16) ^ ((l & 7) << 4));
            bf16x8 av = *reinterpret_cast<const bf16x8*>(buf + rb1);
#pragma unroll
            for (int o16 = 0; o16 < 4; ++o16)
                acc[o16] = __builtin_amdgcn_mfma_f32_16x16x32_bf16(
                               av, bfr[(((it * 8 + w * 2 + 1) * 4) + o16) * 64], acc[o16], 0, 0, 0);
            accz = __builtin_amdgcn_mfma_f32_16x16x32_bf16(av, onesv, accz, 0, 0, 0);
        }
    }

    // Z partials: accz D-frag row=(l>>4)*4+r, col=l&15 (all cols identical)
    if ((l & 15) == 0) {
#pragma unroll
        for (int r = 0; r < 4; ++r) zpart[w][(l >> 4) * 4 + r] = accz[r];
    }
#pragma unroll
    for (int o16 = 0; o16 < 4; ++o16) comb[w][o16][l] = acc[o16];
    __syncthreads();

    // wave w finalizes output column block o16 = w
    f32x4 res = comb[0][w][l];
#pragma unroll
    for (int wp = 1; wp < 4; ++wp) res += comb[wp][w][l];

#pragma unroll
    for (int r = 0; r < 4; ++r) {
        const int row = g * 4 + r;                     // C/D: row=(l>>4)*4+r, col=l&15
        float z = zpart[0][row] + zpart[1][row] + zpart[2][row] + zpart[3][row];
        float v = res[r] / z;
        v = v > 0.f ? v : expm1f(v);                   // ELU
        out[(size_t)(b * Nn + i0 + row) * FOUT + w * 16 + jc] = v;
    }
}

extern "C" void kernel_launch(void* const* d_in, const int* in_sizes, int n_in,
                              void* d_out, int out_size, void* d_ws, size_t ws_size,
                              hipStream_t stream) {
    const float* h   = (const float*)d_in[0];
    const int*   adj = (const int*)d_in[1];
    const float* W   = (const float*)d_in[2];
    const float* a   = (const float*)d_in[3];
    float* out = (float*)d_out;

    __bf16* whfrag = (__bf16*)d_ws;                                   // 2 MB
    float*  fs     = (float*)((char*)d_ws + (size_t)Bb * Nn * FOUT * 2);
    float*  fd     = fs + Bb * Nn;

    gat_k1<<<dim3(Bb * 64), dim3(256), 0, stream>>>(h, W, a, whfrag, fs, fd);
    gat_k2<<<dim3(Bb * 128), dim3(256), 0, stream>>>(adj, whfrag, fs, fd, out);
}